// Round 13
// baseline (426.297 us; speedup 1.0000x reference)
//
#include <hip/hip_runtime.h>
#include <cstdint>
#include <cstddef>

// Problem constants
#define B_N   16384
#define D_DIM 16
#define K_NBR 25
#define CAP   256       // per-row LDS candidate capacity (E[C]~96)
#define MAXL  4         // CAP/64
#define NSAMP 1024      // threshold sample count per row
#define EPAD  20        // u16 row pad for eig staging buffers

// Workspace: accum | sq | T | rawh | rawl | lath | latl | nbrG
#define WS_SQ_OFF   256
#define WS_T_OFF    (WS_SQ_OFF + 65536)
#define WS_RAWH_OFF (WS_T_OFF + 65536)
#define WS_RAWL_OFF (WS_RAWH_OFF + B_N * D_DIM * 2)
#define WS_LATH_OFF (WS_RAWL_OFF + B_N * D_DIM * 2)
#define WS_LATL_OFF (WS_LATH_OFF + B_N * D_DIM * 2)
#define WS_NBR_OFF  (WS_LATL_OFF + B_N * D_DIM * 2)

typedef __attribute__((ext_vector_type(8))) short bf16x8;
typedef __attribute__((ext_vector_type(4))) float f32x4;

__device__ __forceinline__ unsigned map_f32(float x) {
    unsigned u = __float_as_uint(x);
    return (u & 0x80000000u) ? ~u : (u | 0x80000000u); // order-preserving
}

__device__ __forceinline__ unsigned short f2bf(float x) {   // RNE f32->bf16 bits
    unsigned u = __float_as_uint(x);
    unsigned r = (u + 0x7FFFu + ((u >> 16) & 1u)) >> 16;
    return (unsigned short)r;
}
__device__ __forceinline__ float bf2f(unsigned short h) {
    return __uint_as_float(((unsigned)h) << 16);
}

// ---------------------------------------------------------------- prep: sq + recon + bf16 hi/lo splits
__global__ __launch_bounds__(256) void prep_kernel(const float4* __restrict__ rawv,
                                                   const float4* __restrict__ latv,
                                                   const float4* __restrict__ ov,
                                                   const float4* __restrict__ tv,
                                                   float* __restrict__ sq,
                                                   unsigned short* __restrict__ rawh,
                                                   unsigned short* __restrict__ rawl,
                                                   unsigned short* __restrict__ lath,
                                                   unsigned short* __restrict__ latl,
                                                   float* __restrict__ accum) {
    int i = blockIdx.x * 256 + threadIdx.x;
    float v[16];
    {
        float4 r0 = rawv[i*4+0], r1 = rawv[i*4+1], r2 = rawv[i*4+2], r3 = rawv[i*4+3];
        v[0]=r0.x; v[1]=r0.y; v[2]=r0.z; v[3]=r0.w;
        v[4]=r1.x; v[5]=r1.y; v[6]=r1.z; v[7]=r1.w;
        v[8]=r2.x; v[9]=r2.y; v[10]=r2.z; v[11]=r2.w;
        v[12]=r3.x; v[13]=r3.y; v[14]=r3.z; v[15]=r3.w;
    }
    float s = 0.0f;
    unsigned short h[16], l[16];
    #pragma unroll
    for (int k = 0; k < 16; ++k) {
        s = fmaf(v[k], v[k], s);
        unsigned short hh = f2bf(v[k]);
        h[k] = hh;
        l[k] = f2bf(v[k] - bf2f(hh));
    }
    sq[i] = s;
    #pragma unroll
    for (int q = 0; q < 4; ++q) {
        ((ushort4*)(rawh + (size_t)i*16))[q] = make_ushort4(h[q*4], h[q*4+1], h[q*4+2], h[q*4+3]);
        ((ushort4*)(rawl + (size_t)i*16))[q] = make_ushort4(l[q*4], l[q*4+1], l[q*4+2], l[q*4+3]);
    }
    // latent split
    {
        float4 r0 = latv[i*4+0], r1 = latv[i*4+1], r2 = latv[i*4+2], r3 = latv[i*4+3];
        v[0]=r0.x; v[1]=r0.y; v[2]=r0.z; v[3]=r0.w;
        v[4]=r1.x; v[5]=r1.y; v[6]=r1.z; v[7]=r1.w;
        v[8]=r2.x; v[9]=r2.y; v[10]=r2.z; v[11]=r2.w;
        v[12]=r3.x; v[13]=r3.y; v[14]=r3.z; v[15]=r3.w;
        #pragma unroll
        for (int k = 0; k < 16; ++k) {
            unsigned short hh = f2bf(v[k]);
            h[k] = hh;
            l[k] = f2bf(v[k] - bf2f(hh));
        }
        #pragma unroll
        for (int q = 0; q < 4; ++q) {
            ((ushort4*)(lath + (size_t)i*16))[q] = make_ushort4(h[q*4], h[q*4+1], h[q*4+2], h[q*4+3]);
            ((ushort4*)(latl + (size_t)i*16))[q] = make_ushort4(l[q*4], l[q*4+1], l[q*4+2], l[q*4+3]);
        }
    }

    float rs = 0.0f;
    #pragma unroll
    for (int q = 0; q < 4; ++q) {
        float4 o = ov[i*4+q], t = tv[i*4+q];
        float d;
        d = o.x - t.x; rs = fmaf(d, d, rs);
        d = o.y - t.y; rs = fmaf(d, d, rs);
        d = o.z - t.z; rs = fmaf(d, d, rs);
        d = o.w - t.w; rs = fmaf(d, d, rs);
    }
    #pragma unroll
    for (int off = 32; off >= 1; off >>= 1) rs += __shfl_down(rs, off, 64);
    if ((threadIdx.x & 63) == 0) atomicAdd(&accum[0], rs);
}

// ---------------------------------------------------------------- per-row distance threshold, LDS-staged
__global__ __launch_bounds__(256) void thresh_kernel(const float4* __restrict__ rawv,
                                                     const unsigned short* __restrict__ rawh,
                                                     const float* __restrict__ sq,
                                                     float* __restrict__ T) {
    __shared__ unsigned short sampH[NSAMP * 16];
    __shared__ float sampSq[NSAMP];
    __shared__ float V[16][48];

    int tid = threadIdx.x;
    for (int s = tid; s < NSAMP; s += 256) {
        int js = s << 4;
        const uint4* src = (const uint4*)(rawh + (size_t)js * 16);
        ((uint4*)(sampH + s * 16))[0] = src[0];
        ((uint4*)(sampH + s * 16))[1] = src[1];
        sampSq[s] = sq[js];
    }

    int rl   = tid >> 4;
    int sidx = tid & 15;
    int i = blockIdx.x * 16 + rl;

    float a[16];
    {
        float4 r0 = rawv[i*4+0], r1 = rawv[i*4+1], r2 = rawv[i*4+2], r3 = rawv[i*4+3];
        a[0]=r0.x; a[1]=r0.y; a[2]=r0.z; a[3]=r0.w;
        a[4]=r1.x; a[5]=r1.y; a[6]=r1.z; a[7]=r1.w;
        a[8]=r2.x; a[9]=r2.y; a[10]=r2.z; a[11]=r2.w;
        a[12]=r3.x; a[13]=r3.y; a[14]=r3.z; a[15]=r3.w;
    }
    float sqi = sq[i];
    __syncthreads();

    float s0 = 3e37f, s1 = 3e37f, s2 = 3e37f;
    for (int t = 0; t < NSAMP / 16; ++t) {
        int s = t * 16 + sidx;
        const uint4* bp = (const uint4*)(sampH + s * 16);
        uint4 h0 = bp[0], h1 = bp[1];
        float dot = 0.0f;
        unsigned w;
        w = h0.x; dot = fmaf(a[0],  __uint_as_float(w << 16), dot); dot = fmaf(a[1],  __uint_as_float(w & 0xFFFF0000u), dot);
        w = h0.y; dot = fmaf(a[2],  __uint_as_float(w << 16), dot); dot = fmaf(a[3],  __uint_as_float(w & 0xFFFF0000u), dot);
        w = h0.z; dot = fmaf(a[4],  __uint_as_float(w << 16), dot); dot = fmaf(a[5],  __uint_as_float(w & 0xFFFF0000u), dot);
        w = h0.w; dot = fmaf(a[6],  __uint_as_float(w << 16), dot); dot = fmaf(a[7],  __uint_as_float(w & 0xFFFF0000u), dot);
        w = h1.x; dot = fmaf(a[8],  __uint_as_float(w << 16), dot); dot = fmaf(a[9],  __uint_as_float(w & 0xFFFF0000u), dot);
        w = h1.y; dot = fmaf(a[10], __uint_as_float(w << 16), dot); dot = fmaf(a[11], __uint_as_float(w & 0xFFFF0000u), dot);
        w = h1.z; dot = fmaf(a[12], __uint_as_float(w << 16), dot); dot = fmaf(a[13], __uint_as_float(w & 0xFFFF0000u), dot);
        w = h1.w; dot = fmaf(a[14], __uint_as_float(w << 16), dot); dot = fmaf(a[15], __uint_as_float(w & 0xFFFF0000u), dot);
        float cur = sqi + sampSq[s] - 2.0f * dot;
        float lo;
        lo = fminf(s0, cur); cur = fmaxf(s0, cur); s0 = lo;
        lo = fminf(s1, cur); cur = fmaxf(s1, cur); s1 = lo;
        lo = fminf(s2, cur); cur = fmaxf(s2, cur); s2 = lo;
    }

    V[rl][sidx*3+0] = s0; V[rl][sidx*3+1] = s1; V[rl][sidx*3+2] = s2;
    __syncthreads();

    int cl0 = 0, cq0 = 0, cl1 = 0, cq1 = 0, cl2 = 0, cq2 = 0;
    for (int k = 0; k < 48; ++k) {
        float v = V[rl][k];
        cl0 += (v < s0); cq0 += (v <= s0);
        cl1 += (v < s1); cq1 += (v <= s1);
        cl2 += (v < s2); cq2 += (v <= s2);
    }
    if (cl0 <= 5 && 5 < cq0) T[i] = s0 + 0.05f;
    else if (cl1 <= 5 && 5 < cq1) T[i] = s1 + 0.05f;
    else if (cl2 <= 5 && 5 < cq2) T[i] = s2 + 0.05f;
}

// ---------------------------------------------------------------- MFMA scan + select: 32 rows/block, 512 thr
// NOTE: plain __launch_bounds__ only — (256,4) caused a 64-VGPR cap + unified-AGPR split and
// massive scratch spill on gfx950 (R7/R8, 183 MB writes). Do not add the second argument.
__global__ __launch_bounds__(512) void scan_kernel(const unsigned short* __restrict__ rawh,
                                                   const unsigned short* __restrict__ rawl,
                                                   const float* __restrict__ sq,
                                                   const float* __restrict__ T,
                                                   unsigned* __restrict__ nbrG) {
    __shared__ unsigned keyS[32 * CAP];
    __shared__ int      cntS[32];
    __shared__ int      nbrW[32][K_NBR];

    int tid  = threadIdx.x;
    int wave = tid >> 6;
    int lane = tid & 63;
    int quad = lane >> 4;
    int lnib = lane & 15;
    int i0   = blockIdx.x * 32;
    int koff = (quad & 1) * 8;

    if (tid < 32) cntS[tid] = 0;

    const unsigned short* ab = (quad < 2 ? rawh : rawl) + (size_t)(i0 + lnib) * 16 + koff;
    bf16x8 afrag0 = *(const bf16x8*)ab;
    bf16x8 afrag1 = *(const bf16x8*)(ab + 16 * 16);

    float sqi[8], hcut[8];
    #pragma unroll
    for (int r = 0; r < 4; ++r) {
        int m = quad * 4 + r;
        sqi[r]     = sq[i0 + m];
        hcut[r]    = 0.5f * (sqi[r] - T[i0 + m]);
        sqi[4+r]   = sq[i0 + m + 16];
        hcut[4+r]  = 0.5f * (sqi[4+r] - T[i0 + m + 16]);
    }
    __syncthreads();

    for (int t = wave; t < B_N / 16; t += 16) {
        int jA = t * 16 + lnib;
        int jB = jA + 128;
        bf16x8 bhA = *(const bf16x8*)(rawh + (size_t)jA * 16 + koff);
        bf16x8 blA = *(const bf16x8*)(rawl + (size_t)jA * 16 + koff);
        bf16x8 bhB = *(const bf16x8*)(rawh + (size_t)jB * 16 + koff);
        bf16x8 blB = *(const bf16x8*)(rawl + (size_t)jB * 16 + koff);
        float sqjA = sq[jA];
        float sqjB = sq[jB];
        f32x4 a0A = {0,0,0,0}, a1A = {0,0,0,0}, a0B = {0,0,0,0}, a1B = {0,0,0,0};
        a0A = __builtin_amdgcn_mfma_f32_16x16x32_bf16(afrag0, blA, a0A, 0, 0, 0);
        a1A = __builtin_amdgcn_mfma_f32_16x16x32_bf16(afrag1, blA, a1A, 0, 0, 0);
        a0B = __builtin_amdgcn_mfma_f32_16x16x32_bf16(afrag0, blB, a0B, 0, 0, 0);
        a1B = __builtin_amdgcn_mfma_f32_16x16x32_bf16(afrag1, blB, a1B, 0, 0, 0);
        a0A = __builtin_amdgcn_mfma_f32_16x16x32_bf16(afrag0, bhA, a0A, 0, 0, 0);
        a1A = __builtin_amdgcn_mfma_f32_16x16x32_bf16(afrag1, bhA, a1A, 0, 0, 0);
        a0B = __builtin_amdgcn_mfma_f32_16x16x32_bf16(afrag0, bhB, a0B, 0, 0, 0);
        a1B = __builtin_amdgcn_mfma_f32_16x16x32_bf16(afrag1, bhB, a1B, 0, 0, 0);
        #pragma unroll
        for (int r = 0; r < 4; ++r) {
            int m0 = quad * 4 + r, m1 = m0 + 16;
            if ((a0A[r] > fmaf(0.5f, sqjA, hcut[r])) && (jA != i0 + m0)) {
                float d2 = sqi[r] + sqjA - 2.0f * a0A[r];
                int pos = atomicAdd(&cntS[m0], 1);
                if (pos < CAP) keyS[m0 * CAP + pos] = (map_f32(d2) & 0xFFFF0000u) | (unsigned)jA;
            }
            if ((a1A[r] > fmaf(0.5f, sqjA, hcut[4+r])) && (jA != i0 + m1)) {
                float d2 = sqi[4+r] + sqjA - 2.0f * a1A[r];
                int pos = atomicAdd(&cntS[m1], 1);
                if (pos < CAP) keyS[m1 * CAP + pos] = (map_f32(d2) & 0xFFFF0000u) | (unsigned)jA;
            }
            if ((a0B[r] > fmaf(0.5f, sqjB, hcut[r])) && (jB != i0 + m0)) {
                float d2 = sqi[r] + sqjB - 2.0f * a0B[r];
                int pos = atomicAdd(&cntS[m0], 1);
                if (pos < CAP) keyS[m0 * CAP + pos] = (map_f32(d2) & 0xFFFF0000u) | (unsigned)jB;
            }
            if ((a1B[r] > fmaf(0.5f, sqjB, hcut[4+r])) && (jB != i0 + m1)) {
                float d2 = sqi[4+r] + sqjB - 2.0f * a1B[r];
                int pos = atomicAdd(&cntS[m1], 1);
                if (pos < CAP) keyS[m1 * CAP + pos] = (map_f32(d2) & 0xFFFF0000u) | (unsigned)jB;
            }
        }
    }
    __syncthreads();

    unsigned long long ltm = (1ull << lane) - 1ull;
    for (int rr = 0; rr < 4; ++rr) {
        int m  = wave * 4 + rr;
        int pt = i0 + m;
        int C = cntS[m]; C = C < CAP ? C : CAP;
        unsigned kl[MAXL];
        #pragma unroll
        for (int tt = 0; tt < MAXL; ++tt) {
            int c = tt * 64 + lane;
            kl[tt] = (c < C) ? keyS[m * CAP + c] : 0xFFFFFFFFu;
        }
        unsigned lo = 0, hi = 0xFFFFFFFEu;
        for (int it = 0; it < 32 && lo < hi; ++it) {
            unsigned mid = lo + ((hi - lo) >> 1);
            unsigned cc = 0;
            #pragma unroll
            for (int tt = 0; tt < MAXL; ++tt)
                cc += (unsigned)__builtin_popcountll(__ballot(kl[tt] <= mid));
            if (cc >= K_NBR) hi = mid; else lo = mid + 1;
        }
        unsigned T25 = hi;

        int base = 0;
        #pragma unroll
        for (int tt = 0; tt < MAXL; ++tt) {
            bool c = kl[tt] <= T25;
            unsigned long long mk = __ballot(c);
            if (c) {
                int pos = base + __builtin_popcountll(mk & ltm);
                if (pos < K_NBR) nbrW[m][pos] = (int)(kl[tt] & 0xFFFFu);
            }
            base += __builtin_popcountll(mk);
        }
        if (lane == 0) {
            int got = base < K_NBR ? base : K_NBR;
            int pad = (got > 0) ? nbrW[m][0] : pt;
            for (int q = got; q < K_NBR; ++q) nbrW[m][q] = pad;
        }
        if (lane < K_NBR) nbrG[(size_t)pt * K_NBR + lane] = (unsigned)nbrW[m][lane];
    }
}

// ---------------------------------------------------------------- eig v5: MFMA trace, fixed fragment layout
// p^2 = tr(Cz^64 Cx^64) / (tr(Cz^64) tr(Cx^64)).
// BUGFIX (R12 NaN, R11 absmax 0.03): old C round-trip read k=16..31 past the 16-row f32
// buffer (pad + next row = garbage). Now each matrix is staged as 32 u16 rows:
// rows 0..15 = C-hi (bf16), rows 16..31 = C-lo. Frag f -> A=[Ch|Cl], B=[Ch;Cl];
// frag g (rows rotated by 16) -> B=[Cl;Ch]. mfma(f,f)+mfma(f,g) = C^2 exactly; all in-bounds.
__global__ __launch_bounds__(256) void eig_kernel(const unsigned short* __restrict__ lath,
                                                  const unsigned short* __restrict__ latl,
                                                  const unsigned short* __restrict__ rawh,
                                                  const unsigned short* __restrict__ rawl,
                                                  const unsigned* __restrict__ nbrG,
                                                  float* __restrict__ accum) {
    __shared__ unsigned short MS[4][2][2][32 * EPAD];  // [wave][comm][h/l]; rows 25..31 zeroed
    __shared__ unsigned short CH[4][2][32 * EPAD];     // [wave][comm]; rows 0..15 hi, 16..31 lo

    int wave = threadIdx.x >> 6;
    int lane = threadIdx.x & 63;
    int quad = lane >> 4;
    int lnib = lane & 15;
    int pt   = blockIdx.x * 4 + wave;

    // ---- stage: lane -> (comm = lane>>5, row = lane&31)
    {
        int comm = lane >> 5;
        int row  = lane & 31;
        uint2* dh = (uint2*)&MS[wave][comm][0][row * EPAD];
        uint2* dl = (uint2*)&MS[wave][comm][1][row * EPAD];
        if (row < K_NBR) {
            int n = (int)nbrG[(size_t)pt * K_NBR + row];
            const uint2* sh = (const uint2*)((comm ? rawh : lath) + (size_t)n * 16);
            const uint2* sl = (const uint2*)((comm ? rawl : latl) + (size_t)n * 16);
            dh[0] = sh[0]; dh[1] = sh[1]; dh[2] = sh[2]; dh[3] = sh[3];
            dl[0] = sl[0]; dl[1] = sl[1]; dl[2] = sl[2]; dl[3] = sl[3];
        } else {
            uint2 z = make_uint2(0u, 0u);
            dh[0] = z; dh[1] = z; dh[2] = z; dh[3] = z;
            dl[0] = z; dl[1] = z; dl[2] = z; dl[3] = z;
        }
    }
    __syncthreads();

    bf16x8 ones;
    #pragma unroll
    for (int j = 0; j < 8; ++j) ones[j] = (short)0x3F80;

    const unsigned short* Mzh = &MS[wave][0][0][0];
    const unsigned short* Mzl = &MS[wave][0][1][0];
    const unsigned short* Mxh = &MS[wave][1][0][0];
    const unsigned short* Mxl = &MS[wave][1][1][0];

    // column-read frags for both communities (A-content == B-content); M has 32 rows -> in-bounds
    bf16x8 fzh, fzl, fxh, fxl;
    #pragma unroll
    for (int j = 0; j < 8; ++j) {
        int k = quad * 8 + j;
        fzh[j] = (short)Mzh[k * EPAD + lnib];
        fzl[j] = (short)Mzl[k * EPAD + lnib];
        fxh[j] = (short)Mxh[k * EPAD + lnib];
        fxl[j] = (short)Mxl[k * EPAD + lnib];
    }

    // M^T M and colsums, Z/X interleaved
    f32x4 mz = {0.f,0.f,0.f,0.f}, mx = {0.f,0.f,0.f,0.f};
    mz = __builtin_amdgcn_mfma_f32_16x16x32_bf16(fzh, fzh, mz, 0, 0, 0);
    mx = __builtin_amdgcn_mfma_f32_16x16x32_bf16(fxh, fxh, mx, 0, 0, 0);
    mz = __builtin_amdgcn_mfma_f32_16x16x32_bf16(fzh, fzl, mz, 0, 0, 0);
    mx = __builtin_amdgcn_mfma_f32_16x16x32_bf16(fxh, fxl, mx, 0, 0, 0);
    mz = __builtin_amdgcn_mfma_f32_16x16x32_bf16(fzl, fzh, mz, 0, 0, 0);
    mx = __builtin_amdgcn_mfma_f32_16x16x32_bf16(fxl, fxh, mx, 0, 0, 0);
    f32x4 dz1 = {0.f,0.f,0.f,0.f}, dx1 = {0.f,0.f,0.f,0.f};
    dz1 = __builtin_amdgcn_mfma_f32_16x16x32_bf16(fzh, ones, dz1, 0, 0, 0);
    dx1 = __builtin_amdgcn_mfma_f32_16x16x32_bf16(fxh, ones, dx1, 0, 0, 0);
    dz1 = __builtin_amdgcn_mfma_f32_16x16x32_bf16(fzl, ones, dz1, 0, 0, 0);
    dx1 = __builtin_amdgcn_mfma_f32_16x16x32_bf16(fxl, ones, dx1, 0, 0, 0);
    f32x4 dz2 = {0.f,0.f,0.f,0.f}, dx2 = {0.f,0.f,0.f,0.f};
    dz2 = __builtin_amdgcn_mfma_f32_16x16x32_bf16(ones, fzh, dz2, 0, 0, 0);
    dx2 = __builtin_amdgcn_mfma_f32_16x16x32_bf16(ones, fxh, dx2, 0, 0, 0);
    dz2 = __builtin_amdgcn_mfma_f32_16x16x32_bf16(ones, fzl, dz2, 0, 0, 0);
    dx2 = __builtin_amdgcn_mfma_f32_16x16x32_bf16(ones, fxl, dx2, 0, 0, 0);

    f32x4 az, ax;
    #pragma unroll
    for (int r = 0; r < 4; ++r) {
        az[r] = mz[r] - dz1[r] * dz2[r] * 0.04f;
        ax[r] = mx[r] - dx1[r] * dx2[r] * 0.04f;
    }

    bool dg = (quad == (lnib >> 2));   // lane's az[lnib&3] is a diagonal element

    // initial trace-normalize (interleaved)
    {
        float tz = dg ? az[lnib & 3] : 0.0f;
        float tx = dg ? ax[lnib & 3] : 0.0f;
        #pragma unroll
        for (int off = 1; off < 64; off <<= 1) {
            tz += __shfl_xor(tz, off, 64);
            tx += __shfl_xor(tx, off, 64);
        }
        float iz = 1.0f / fmaxf(tz, 1e-30f), ix = 1.0f / fmaxf(tx, 1e-30f);
        #pragma unroll
        for (int r = 0; r < 4; ++r) { az[r] *= iz; ax[r] *= ix; }
    }

    // 6 squarings -> C^64; renormalize after squaring 3 only
    // (PSD trace-normalized: entries <= 1, trace of 8th power >= 16^-8 = 2^-32 -> fp32-safe)
    unsigned short* Bz = &CH[wave][0][0];
    unsigned short* Bx = &CH[wave][1][0];
    for (int s = 0; s < 6; ++s) {
        #pragma unroll
        for (int r = 0; r < 4; ++r) {
            int row = quad * 4 + r;
            unsigned short zh = f2bf(az[r]);
            unsigned short xh = f2bf(ax[r]);
            Bz[row * EPAD + lnib]        = zh;
            Bx[row * EPAD + lnib]        = xh;
            Bz[(row + 16) * EPAD + lnib] = f2bf(az[r] - bf2f(zh));
            Bx[(row + 16) * EPAD + lnib] = f2bf(ax[r] - bf2f(xh));
        }
        // frags: f = rows k (hi;lo), g = rows (k+16)&31 (lo;hi); all reads in 0..31 rows
        bf16x8 fz, gz, fx, gx;
        #pragma unroll
        for (int j = 0; j < 8; ++j) {
            int k  = quad * 8 + j;
            int ks = (k + 16) & 31;
            fz[j] = (short)Bz[k  * EPAD + lnib];
            gz[j] = (short)Bz[ks * EPAD + lnib];
            fx[j] = (short)Bx[k  * EPAD + lnib];
            gx[j] = (short)Bx[ks * EPAD + lnib];
        }
        // C^2 = (Ch^2 + Cl^2) + (Ch Cl + Cl Ch)
        f32x4 nz = {0.f,0.f,0.f,0.f}, nx = {0.f,0.f,0.f,0.f};
        nz = __builtin_amdgcn_mfma_f32_16x16x32_bf16(fz, fz, nz, 0, 0, 0);
        nx = __builtin_amdgcn_mfma_f32_16x16x32_bf16(fx, fx, nx, 0, 0, 0);
        nz = __builtin_amdgcn_mfma_f32_16x16x32_bf16(fz, gz, nz, 0, 0, 0);
        nx = __builtin_amdgcn_mfma_f32_16x16x32_bf16(fx, gx, nx, 0, 0, 0);
        if (s == 2) {
            float tz = dg ? nz[lnib & 3] : 0.0f;
            float tx = dg ? nx[lnib & 3] : 0.0f;
            #pragma unroll
            for (int off = 1; off < 64; off <<= 1) {
                tz += __shfl_xor(tz, off, 64);
                tx += __shfl_xor(tx, off, 64);
            }
            float iz = 1.0f / fmaxf(tz, 1e-30f), ix = 1.0f / fmaxf(tx, 1e-30f);
            #pragma unroll
            for (int r = 0; r < 4; ++r) { az[r] = nz[r] * iz; ax[r] = nx[r] * ix; }
        } else {
            #pragma unroll
            for (int r = 0; r < 4; ++r) { az[r] = nz[r]; ax[r] = nx[r]; }
        }
    }

    // final: p^2 = tr(Cz64 Cx64)/(tr(Cz64) tr(Cx64)); 3 interleaved reduces
    float tz = dg ? az[lnib & 3] : 0.0f;
    float tx = dg ? ax[lnib & 3] : 0.0f;
    float dt = az[0]*ax[0] + az[1]*ax[1] + az[2]*ax[2] + az[3]*ax[3];
    #pragma unroll
    for (int off = 1; off < 64; off <<= 1) {
        tz += __shfl_xor(tz, off, 64);
        tx += __shfl_xor(tx, off, 64);
        dt += __shfl_xor(dt, off, 64);
    }
    if (lane == 0) atomicAdd(&accum[1], dt / fmaxf(tz * tx, 1e-30f));
}

// ---------------------------------------------------------------- combine
__global__ void final_kernel(const float* __restrict__ accum, float* __restrict__ out) {
    float recon = accum[0] * (1.0f / (float)(B_N * D_DIM));
    float tsa   = 2.0f - 2.0f * (accum[1] * (1.0f / (float)B_N));
    out[0] = recon + 0.1f * tsa;
}

extern "C" void kernel_launch(void* const* d_in, const int* in_sizes, int n_in,
                              void* d_out, int out_size, void* d_ws, size_t ws_size,
                              hipStream_t stream) {
    const float* outputs = (const float*)d_in[0];
    const float* targets = (const float*)d_in[1];
    const float* latent  = (const float*)d_in[2];
    const float* raw     = (const float*)d_in[3];

    float* accum         = (float*)d_ws;
    float* sq            = (float*)((char*)d_ws + WS_SQ_OFF);
    float* T             = (float*)((char*)d_ws + WS_T_OFF);
    unsigned short* rawh = (unsigned short*)((char*)d_ws + WS_RAWH_OFF);
    unsigned short* rawl = (unsigned short*)((char*)d_ws + WS_RAWL_OFF);
    unsigned short* lath = (unsigned short*)((char*)d_ws + WS_LATH_OFF);
    unsigned short* latl = (unsigned short*)((char*)d_ws + WS_LATL_OFF);
    unsigned* nbrG       = (unsigned*)((char*)d_ws + WS_NBR_OFF);

    const float4* rawv = (const float4*)raw;
    const float4* latv = (const float4*)latent;

    hipMemsetAsync(d_ws, 0, 256, stream);  // zero accum
    prep_kernel<<<B_N / 256, 256, 0, stream>>>(rawv, latv, (const float4*)outputs,
                                               (const float4*)targets, sq, rawh, rawl,
                                               lath, latl, accum);
    thresh_kernel<<<B_N / 16, 256, 0, stream>>>(rawv, rawh, sq, T);
    scan_kernel<<<B_N / 32, 512, 0, stream>>>(rawh, rawl, sq, T, nbrG);
    eig_kernel<<<B_N / 4, 256, 0, stream>>>(lath, latl, rawh, rawl, nbrG, accum);
    final_kernel<<<1, 1, 0, stream>>>(accum, (float*)d_out);
}

// Round 14
// 248.386 us; speedup vs baseline: 1.7163x; 1.7163x over previous
//
#include <hip/hip_runtime.h>
#include <cstdint>
#include <cstddef>

// Problem constants
#define B_N   16384
#define D_DIM 16
#define K_NBR 25
#define CAP   256       // per-row LDS candidate capacity (E[C]~96)
#define MAXL  4         // CAP/64
#define NSAMP 1024      // threshold sample count per row
#define EPAD  20        // u16 row pad for eig staging buffers
#define NPART (B_N / 4) // per-block partials from eig (4096)

// Workspace: accum | sq | T | rawh | rawl | lath | latl | nbrG | part
#define WS_SQ_OFF   256
#define WS_T_OFF    (WS_SQ_OFF + 65536)
#define WS_RAWH_OFF (WS_T_OFF + 65536)
#define WS_RAWL_OFF (WS_RAWH_OFF + B_N * D_DIM * 2)
#define WS_LATH_OFF (WS_RAWL_OFF + B_N * D_DIM * 2)
#define WS_LATL_OFF (WS_LATH_OFF + B_N * D_DIM * 2)
#define WS_NBR_OFF  (WS_LATL_OFF + B_N * D_DIM * 2)
#define WS_PART_OFF (WS_NBR_OFF + B_N * K_NBR * 4)

typedef __attribute__((ext_vector_type(8))) short bf16x8;
typedef __attribute__((ext_vector_type(4))) float f32x4;

__device__ __forceinline__ unsigned map_f32(float x) {
    unsigned u = __float_as_uint(x);
    return (u & 0x80000000u) ? ~u : (u | 0x80000000u); // order-preserving
}

__device__ __forceinline__ unsigned short f2bf(float x) {   // RNE f32->bf16 bits
    unsigned u = __float_as_uint(x);
    unsigned r = (u + 0x7FFFu + ((u >> 16) & 1u)) >> 16;
    return (unsigned short)r;
}
__device__ __forceinline__ float bf2f(unsigned short h) {
    return __uint_as_float(((unsigned)h) << 16);
}

// ---------------------------------------------------------------- prep: sq + recon + bf16 hi/lo splits
__global__ __launch_bounds__(256) void prep_kernel(const float4* __restrict__ rawv,
                                                   const float4* __restrict__ latv,
                                                   const float4* __restrict__ ov,
                                                   const float4* __restrict__ tv,
                                                   float* __restrict__ sq,
                                                   unsigned short* __restrict__ rawh,
                                                   unsigned short* __restrict__ rawl,
                                                   unsigned short* __restrict__ lath,
                                                   unsigned short* __restrict__ latl,
                                                   float* __restrict__ accum) {
    int i = blockIdx.x * 256 + threadIdx.x;
    float v[16];
    {
        float4 r0 = rawv[i*4+0], r1 = rawv[i*4+1], r2 = rawv[i*4+2], r3 = rawv[i*4+3];
        v[0]=r0.x; v[1]=r0.y; v[2]=r0.z; v[3]=r0.w;
        v[4]=r1.x; v[5]=r1.y; v[6]=r1.z; v[7]=r1.w;
        v[8]=r2.x; v[9]=r2.y; v[10]=r2.z; v[11]=r2.w;
        v[12]=r3.x; v[13]=r3.y; v[14]=r3.z; v[15]=r3.w;
    }
    float s = 0.0f;
    unsigned short h[16], l[16];
    #pragma unroll
    for (int k = 0; k < 16; ++k) {
        s = fmaf(v[k], v[k], s);
        unsigned short hh = f2bf(v[k]);
        h[k] = hh;
        l[k] = f2bf(v[k] - bf2f(hh));
    }
    sq[i] = s;
    #pragma unroll
    for (int q = 0; q < 4; ++q) {
        ((ushort4*)(rawh + (size_t)i*16))[q] = make_ushort4(h[q*4], h[q*4+1], h[q*4+2], h[q*4+3]);
        ((ushort4*)(rawl + (size_t)i*16))[q] = make_ushort4(l[q*4], l[q*4+1], l[q*4+2], l[q*4+3]);
    }
    // latent split
    {
        float4 r0 = latv[i*4+0], r1 = latv[i*4+1], r2 = latv[i*4+2], r3 = latv[i*4+3];
        v[0]=r0.x; v[1]=r0.y; v[2]=r0.z; v[3]=r0.w;
        v[4]=r1.x; v[5]=r1.y; v[6]=r1.z; v[7]=r1.w;
        v[8]=r2.x; v[9]=r2.y; v[10]=r2.z; v[11]=r2.w;
        v[12]=r3.x; v[13]=r3.y; v[14]=r3.z; v[15]=r3.w;
        #pragma unroll
        for (int k = 0; k < 16; ++k) {
            unsigned short hh = f2bf(v[k]);
            h[k] = hh;
            l[k] = f2bf(v[k] - bf2f(hh));
        }
        #pragma unroll
        for (int q = 0; q < 4; ++q) {
            ((ushort4*)(lath + (size_t)i*16))[q] = make_ushort4(h[q*4], h[q*4+1], h[q*4+2], h[q*4+3]);
            ((ushort4*)(latl + (size_t)i*16))[q] = make_ushort4(l[q*4], l[q*4+1], l[q*4+2], l[q*4+3]);
        }
    }

    float rs = 0.0f;
    #pragma unroll
    for (int q = 0; q < 4; ++q) {
        float4 o = ov[i*4+q], t = tv[i*4+q];
        float d;
        d = o.x - t.x; rs = fmaf(d, d, rs);
        d = o.y - t.y; rs = fmaf(d, d, rs);
        d = o.z - t.z; rs = fmaf(d, d, rs);
        d = o.w - t.w; rs = fmaf(d, d, rs);
    }
    #pragma unroll
    for (int off = 32; off >= 1; off >>= 1) rs += __shfl_down(rs, off, 64);
    if ((threadIdx.x & 63) == 0) atomicAdd(&accum[0], rs);   // 256 atomics total: negligible
}

// ---------------------------------------------------------------- per-row distance threshold, LDS-staged
__global__ __launch_bounds__(256) void thresh_kernel(const float4* __restrict__ rawv,
                                                     const unsigned short* __restrict__ rawh,
                                                     const float* __restrict__ sq,
                                                     float* __restrict__ T) {
    __shared__ unsigned short sampH[NSAMP * 16];
    __shared__ float sampSq[NSAMP];
    __shared__ float V[16][48];

    int tid = threadIdx.x;
    for (int s = tid; s < NSAMP; s += 256) {
        int js = s << 4;
        const uint4* src = (const uint4*)(rawh + (size_t)js * 16);
        ((uint4*)(sampH + s * 16))[0] = src[0];
        ((uint4*)(sampH + s * 16))[1] = src[1];
        sampSq[s] = sq[js];
    }

    int rl   = tid >> 4;
    int sidx = tid & 15;
    int i = blockIdx.x * 16 + rl;

    float a[16];
    {
        float4 r0 = rawv[i*4+0], r1 = rawv[i*4+1], r2 = rawv[i*4+2], r3 = rawv[i*4+3];
        a[0]=r0.x; a[1]=r0.y; a[2]=r0.z; a[3]=r0.w;
        a[4]=r1.x; a[5]=r1.y; a[6]=r1.z; a[7]=r1.w;
        a[8]=r2.x; a[9]=r2.y; a[10]=r2.z; a[11]=r2.w;
        a[12]=r3.x; a[13]=r3.y; a[14]=r3.z; a[15]=r3.w;
    }
    float sqi = sq[i];
    __syncthreads();

    float s0 = 3e37f, s1 = 3e37f, s2 = 3e37f;
    for (int t = 0; t < NSAMP / 16; ++t) {
        int s = t * 16 + sidx;
        const uint4* bp = (const uint4*)(sampH + s * 16);
        uint4 h0 = bp[0], h1 = bp[1];
        float dot = 0.0f;
        unsigned w;
        w = h0.x; dot = fmaf(a[0],  __uint_as_float(w << 16), dot); dot = fmaf(a[1],  __uint_as_float(w & 0xFFFF0000u), dot);
        w = h0.y; dot = fmaf(a[2],  __uint_as_float(w << 16), dot); dot = fmaf(a[3],  __uint_as_float(w & 0xFFFF0000u), dot);
        w = h0.z; dot = fmaf(a[4],  __uint_as_float(w << 16), dot); dot = fmaf(a[5],  __uint_as_float(w & 0xFFFF0000u), dot);
        w = h0.w; dot = fmaf(a[6],  __uint_as_float(w << 16), dot); dot = fmaf(a[7],  __uint_as_float(w & 0xFFFF0000u), dot);
        w = h1.x; dot = fmaf(a[8],  __uint_as_float(w << 16), dot); dot = fmaf(a[9],  __uint_as_float(w & 0xFFFF0000u), dot);
        w = h1.y; dot = fmaf(a[10], __uint_as_float(w << 16), dot); dot = fmaf(a[11], __uint_as_float(w & 0xFFFF0000u), dot);
        w = h1.z; dot = fmaf(a[12], __uint_as_float(w << 16), dot); dot = fmaf(a[13], __uint_as_float(w & 0xFFFF0000u), dot);
        w = h1.w; dot = fmaf(a[14], __uint_as_float(w << 16), dot); dot = fmaf(a[15], __uint_as_float(w & 0xFFFF0000u), dot);
        float cur = sqi + sampSq[s] - 2.0f * dot;
        float lo;
        lo = fminf(s0, cur); cur = fmaxf(s0, cur); s0 = lo;
        lo = fminf(s1, cur); cur = fmaxf(s1, cur); s1 = lo;
        lo = fminf(s2, cur); cur = fmaxf(s2, cur); s2 = lo;
    }

    V[rl][sidx*3+0] = s0; V[rl][sidx*3+1] = s1; V[rl][sidx*3+2] = s2;
    __syncthreads();

    int cl0 = 0, cq0 = 0, cl1 = 0, cq1 = 0, cl2 = 0, cq2 = 0;
    for (int k = 0; k < 48; ++k) {
        float v = V[rl][k];
        cl0 += (v < s0); cq0 += (v <= s0);
        cl1 += (v < s1); cq1 += (v <= s1);
        cl2 += (v < s2); cq2 += (v <= s2);
    }
    if (cl0 <= 5 && 5 < cq0) T[i] = s0 + 0.05f;
    else if (cl1 <= 5 && 5 < cq1) T[i] = s1 + 0.05f;
    else if (cl2 <= 5 && 5 < cq2) T[i] = s2 + 0.05f;
}

// ---------------------------------------------------------------- MFMA scan + select: 32 rows/block, 512 thr
// NOTE: plain __launch_bounds__ only — (256,4) caused a 64-VGPR cap + unified-AGPR split and
// massive scratch spill on gfx950 (R7/R8, 183 MB writes). Do not add the second argument.
__global__ __launch_bounds__(512) void scan_kernel(const unsigned short* __restrict__ rawh,
                                                   const unsigned short* __restrict__ rawl,
                                                   const float* __restrict__ sq,
                                                   const float* __restrict__ T,
                                                   unsigned* __restrict__ nbrG) {
    __shared__ unsigned keyS[32 * CAP];
    __shared__ int      cntS[32];
    __shared__ int      nbrW[32][K_NBR];

    int tid  = threadIdx.x;
    int wave = tid >> 6;
    int lane = tid & 63;
    int quad = lane >> 4;
    int lnib = lane & 15;
    int i0   = blockIdx.x * 32;
    int koff = (quad & 1) * 8;

    if (tid < 32) cntS[tid] = 0;

    const unsigned short* ab = (quad < 2 ? rawh : rawl) + (size_t)(i0 + lnib) * 16 + koff;
    bf16x8 afrag0 = *(const bf16x8*)ab;
    bf16x8 afrag1 = *(const bf16x8*)(ab + 16 * 16);

    float sqi[8], hcut[8];
    #pragma unroll
    for (int r = 0; r < 4; ++r) {
        int m = quad * 4 + r;
        sqi[r]     = sq[i0 + m];
        hcut[r]    = 0.5f * (sqi[r] - T[i0 + m]);
        sqi[4+r]   = sq[i0 + m + 16];
        hcut[4+r]  = 0.5f * (sqi[4+r] - T[i0 + m + 16]);
    }
    __syncthreads();

    for (int t = wave; t < B_N / 16; t += 16) {
        int jA = t * 16 + lnib;
        int jB = jA + 128;
        bf16x8 bhA = *(const bf16x8*)(rawh + (size_t)jA * 16 + koff);
        bf16x8 blA = *(const bf16x8*)(rawl + (size_t)jA * 16 + koff);
        bf16x8 bhB = *(const bf16x8*)(rawh + (size_t)jB * 16 + koff);
        bf16x8 blB = *(const bf16x8*)(rawl + (size_t)jB * 16 + koff);
        float sqjA = sq[jA];
        float sqjB = sq[jB];
        f32x4 a0A = {0,0,0,0}, a1A = {0,0,0,0}, a0B = {0,0,0,0}, a1B = {0,0,0,0};
        a0A = __builtin_amdgcn_mfma_f32_16x16x32_bf16(afrag0, blA, a0A, 0, 0, 0);
        a1A = __builtin_amdgcn_mfma_f32_16x16x32_bf16(afrag1, blA, a1A, 0, 0, 0);
        a0B = __builtin_amdgcn_mfma_f32_16x16x32_bf16(afrag0, blB, a0B, 0, 0, 0);
        a1B = __builtin_amdgcn_mfma_f32_16x16x32_bf16(afrag1, blB, a1B, 0, 0, 0);
        a0A = __builtin_amdgcn_mfma_f32_16x16x32_bf16(afrag0, bhA, a0A, 0, 0, 0);
        a1A = __builtin_amdgcn_mfma_f32_16x16x32_bf16(afrag1, bhA, a1A, 0, 0, 0);
        a0B = __builtin_amdgcn_mfma_f32_16x16x32_bf16(afrag0, bhB, a0B, 0, 0, 0);
        a1B = __builtin_amdgcn_mfma_f32_16x16x32_bf16(afrag1, bhB, a1B, 0, 0, 0);
        #pragma unroll
        for (int r = 0; r < 4; ++r) {
            int m0 = quad * 4 + r, m1 = m0 + 16;
            if ((a0A[r] > fmaf(0.5f, sqjA, hcut[r])) && (jA != i0 + m0)) {
                float d2 = sqi[r] + sqjA - 2.0f * a0A[r];
                int pos = atomicAdd(&cntS[m0], 1);
                if (pos < CAP) keyS[m0 * CAP + pos] = (map_f32(d2) & 0xFFFF0000u) | (unsigned)jA;
            }
            if ((a1A[r] > fmaf(0.5f, sqjA, hcut[4+r])) && (jA != i0 + m1)) {
                float d2 = sqi[4+r] + sqjA - 2.0f * a1A[r];
                int pos = atomicAdd(&cntS[m1], 1);
                if (pos < CAP) keyS[m1 * CAP + pos] = (map_f32(d2) & 0xFFFF0000u) | (unsigned)jA;
            }
            if ((a0B[r] > fmaf(0.5f, sqjB, hcut[r])) && (jB != i0 + m0)) {
                float d2 = sqi[r] + sqjB - 2.0f * a0B[r];
                int pos = atomicAdd(&cntS[m0], 1);
                if (pos < CAP) keyS[m0 * CAP + pos] = (map_f32(d2) & 0xFFFF0000u) | (unsigned)jB;
            }
            if ((a1B[r] > fmaf(0.5f, sqjB, hcut[4+r])) && (jB != i0 + m1)) {
                float d2 = sqi[4+r] + sqjB - 2.0f * a1B[r];
                int pos = atomicAdd(&cntS[m1], 1);
                if (pos < CAP) keyS[m1 * CAP + pos] = (map_f32(d2) & 0xFFFF0000u) | (unsigned)jB;
            }
        }
    }
    __syncthreads();

    unsigned long long ltm = (1ull << lane) - 1ull;
    for (int rr = 0; rr < 4; ++rr) {
        int m  = wave * 4 + rr;
        int pt = i0 + m;
        int C = cntS[m]; C = C < CAP ? C : CAP;
        unsigned kl[MAXL];
        #pragma unroll
        for (int tt = 0; tt < MAXL; ++tt) {
            int c = tt * 64 + lane;
            kl[tt] = (c < C) ? keyS[m * CAP + c] : 0xFFFFFFFFu;
        }
        unsigned lo = 0, hi = 0xFFFFFFFEu;
        for (int it = 0; it < 32 && lo < hi; ++it) {
            unsigned mid = lo + ((hi - lo) >> 1);
            unsigned cc = 0;
            #pragma unroll
            for (int tt = 0; tt < MAXL; ++tt)
                cc += (unsigned)__builtin_popcountll(__ballot(kl[tt] <= mid));
            if (cc >= K_NBR) hi = mid; else lo = mid + 1;
        }
        unsigned T25 = hi;

        int base = 0;
        #pragma unroll
        for (int tt = 0; tt < MAXL; ++tt) {
            bool c = kl[tt] <= T25;
            unsigned long long mk = __ballot(c);
            if (c) {
                int pos = base + __builtin_popcountll(mk & ltm);
                if (pos < K_NBR) nbrW[m][pos] = (int)(kl[tt] & 0xFFFFu);
            }
            base += __builtin_popcountll(mk);
        }
        if (lane == 0) {
            int got = base < K_NBR ? base : K_NBR;
            int pad = (got > 0) ? nbrW[m][0] : pt;
            for (int q = got; q < K_NBR; ++q) nbrW[m][q] = pad;
        }
        if (lane < K_NBR) nbrG[(size_t)pt * K_NBR + lane] = (unsigned)nbrW[m][lane];
    }
}

// ---------------------------------------------------------------- eig v6: MFMA trace; per-block partial (NO global atomic)
// R13 post-mortem: 16384 same-address atomicAdds serialized at L2 (~220 us floor across
// R6/R9/R10/R11/R13). Now: LDS-reduce the 4 wave results -> part[blockIdx]; final reduces.
__global__ __launch_bounds__(256) void eig_kernel(const unsigned short* __restrict__ lath,
                                                  const unsigned short* __restrict__ latl,
                                                  const unsigned short* __restrict__ rawh,
                                                  const unsigned short* __restrict__ rawl,
                                                  const unsigned* __restrict__ nbrG,
                                                  float* __restrict__ part) {
    __shared__ unsigned short MS[4][2][2][32 * EPAD];  // [wave][comm][h/l]; rows 25..31 zeroed
    __shared__ unsigned short CH[4][2][32 * EPAD];     // [wave][comm]; rows 0..15 hi, 16..31 lo
    __shared__ float psum[4];

    int wave = threadIdx.x >> 6;
    int lane = threadIdx.x & 63;
    int quad = lane >> 4;
    int lnib = lane & 15;
    int pt   = blockIdx.x * 4 + wave;

    // ---- stage: lane -> (comm = lane>>5, row = lane&31)
    {
        int comm = lane >> 5;
        int row  = lane & 31;
        uint2* dh = (uint2*)&MS[wave][comm][0][row * EPAD];
        uint2* dl = (uint2*)&MS[wave][comm][1][row * EPAD];
        if (row < K_NBR) {
            int n = (int)nbrG[(size_t)pt * K_NBR + row];
            const uint2* sh = (const uint2*)((comm ? rawh : lath) + (size_t)n * 16);
            const uint2* sl = (const uint2*)((comm ? rawl : latl) + (size_t)n * 16);
            dh[0] = sh[0]; dh[1] = sh[1]; dh[2] = sh[2]; dh[3] = sh[3];
            dl[0] = sl[0]; dl[1] = sl[1]; dl[2] = sl[2]; dl[3] = sl[3];
        } else {
            uint2 z = make_uint2(0u, 0u);
            dh[0] = z; dh[1] = z; dh[2] = z; dh[3] = z;
            dl[0] = z; dl[1] = z; dl[2] = z; dl[3] = z;
        }
    }
    __syncthreads();

    bf16x8 ones;
    #pragma unroll
    for (int j = 0; j < 8; ++j) ones[j] = (short)0x3F80;

    const unsigned short* Mzh = &MS[wave][0][0][0];
    const unsigned short* Mzl = &MS[wave][0][1][0];
    const unsigned short* Mxh = &MS[wave][1][0][0];
    const unsigned short* Mxl = &MS[wave][1][1][0];

    bf16x8 fzh, fzl, fxh, fxl;
    #pragma unroll
    for (int j = 0; j < 8; ++j) {
        int k = quad * 8 + j;
        fzh[j] = (short)Mzh[k * EPAD + lnib];
        fzl[j] = (short)Mzl[k * EPAD + lnib];
        fxh[j] = (short)Mxh[k * EPAD + lnib];
        fxl[j] = (short)Mxl[k * EPAD + lnib];
    }

    // M^T M and colsums, Z/X interleaved
    f32x4 mz = {0.f,0.f,0.f,0.f}, mx = {0.f,0.f,0.f,0.f};
    mz = __builtin_amdgcn_mfma_f32_16x16x32_bf16(fzh, fzh, mz, 0, 0, 0);
    mx = __builtin_amdgcn_mfma_f32_16x16x32_bf16(fxh, fxh, mx, 0, 0, 0);
    mz = __builtin_amdgcn_mfma_f32_16x16x32_bf16(fzh, fzl, mz, 0, 0, 0);
    mx = __builtin_amdgcn_mfma_f32_16x16x32_bf16(fxh, fxl, mx, 0, 0, 0);
    mz = __builtin_amdgcn_mfma_f32_16x16x32_bf16(fzl, fzh, mz, 0, 0, 0);
    mx = __builtin_amdgcn_mfma_f32_16x16x32_bf16(fxl, fxh, mx, 0, 0, 0);
    f32x4 dz1 = {0.f,0.f,0.f,0.f}, dx1 = {0.f,0.f,0.f,0.f};
    dz1 = __builtin_amdgcn_mfma_f32_16x16x32_bf16(fzh, ones, dz1, 0, 0, 0);
    dx1 = __builtin_amdgcn_mfma_f32_16x16x32_bf16(fxh, ones, dx1, 0, 0, 0);
    dz1 = __builtin_amdgcn_mfma_f32_16x16x32_bf16(fzl, ones, dz1, 0, 0, 0);
    dx1 = __builtin_amdgcn_mfma_f32_16x16x32_bf16(fxl, ones, dx1, 0, 0, 0);
    f32x4 dz2 = {0.f,0.f,0.f,0.f}, dx2 = {0.f,0.f,0.f,0.f};
    dz2 = __builtin_amdgcn_mfma_f32_16x16x32_bf16(ones, fzh, dz2, 0, 0, 0);
    dx2 = __builtin_amdgcn_mfma_f32_16x16x32_bf16(ones, fxh, dx2, 0, 0, 0);
    dz2 = __builtin_amdgcn_mfma_f32_16x16x32_bf16(ones, fzl, dz2, 0, 0, 0);
    dx2 = __builtin_amdgcn_mfma_f32_16x16x32_bf16(ones, fxl, dx2, 0, 0, 0);

    f32x4 az, ax;
    #pragma unroll
    for (int r = 0; r < 4; ++r) {
        az[r] = mz[r] - dz1[r] * dz2[r] * 0.04f;
        ax[r] = mx[r] - dx1[r] * dx2[r] * 0.04f;
    }

    bool dg = (quad == (lnib >> 2));

    // initial trace-normalize (interleaved)
    {
        float tz = dg ? az[lnib & 3] : 0.0f;
        float tx = dg ? ax[lnib & 3] : 0.0f;
        #pragma unroll
        for (int off = 1; off < 64; off <<= 1) {
            tz += __shfl_xor(tz, off, 64);
            tx += __shfl_xor(tx, off, 64);
        }
        float iz = 1.0f / fmaxf(tz, 1e-30f), ix = 1.0f / fmaxf(tx, 1e-30f);
        #pragma unroll
        for (int r = 0; r < 4; ++r) { az[r] *= iz; ax[r] *= ix; }
    }

    // 6 squarings -> C^64; renormalize after squaring 3 only
    unsigned short* Bz = &CH[wave][0][0];
    unsigned short* Bx = &CH[wave][1][0];
    for (int s = 0; s < 6; ++s) {
        #pragma unroll
        for (int r = 0; r < 4; ++r) {
            int row = quad * 4 + r;
            unsigned short zh = f2bf(az[r]);
            unsigned short xh = f2bf(ax[r]);
            Bz[row * EPAD + lnib]        = zh;
            Bx[row * EPAD + lnib]        = xh;
            Bz[(row + 16) * EPAD + lnib] = f2bf(az[r] - bf2f(zh));
            Bx[(row + 16) * EPAD + lnib] = f2bf(ax[r] - bf2f(xh));
        }
        bf16x8 fz, gz, fx, gx;
        #pragma unroll
        for (int j = 0; j < 8; ++j) {
            int k  = quad * 8 + j;
            int ks = (k + 16) & 31;
            fz[j] = (short)Bz[k  * EPAD + lnib];
            gz[j] = (short)Bz[ks * EPAD + lnib];
            fx[j] = (short)Bx[k  * EPAD + lnib];
            gx[j] = (short)Bx[ks * EPAD + lnib];
        }
        f32x4 nz = {0.f,0.f,0.f,0.f}, nx = {0.f,0.f,0.f,0.f};
        nz = __builtin_amdgcn_mfma_f32_16x16x32_bf16(fz, fz, nz, 0, 0, 0);
        nx = __builtin_amdgcn_mfma_f32_16x16x32_bf16(fx, fx, nx, 0, 0, 0);
        nz = __builtin_amdgcn_mfma_f32_16x16x32_bf16(fz, gz, nz, 0, 0, 0);
        nx = __builtin_amdgcn_mfma_f32_16x16x32_bf16(fx, gx, nx, 0, 0, 0);
        if (s == 2) {
            float tz = dg ? nz[lnib & 3] : 0.0f;
            float tx = dg ? nx[lnib & 3] : 0.0f;
            #pragma unroll
            for (int off = 1; off < 64; off <<= 1) {
                tz += __shfl_xor(tz, off, 64);
                tx += __shfl_xor(tx, off, 64);
            }
            float iz = 1.0f / fmaxf(tz, 1e-30f), ix = 1.0f / fmaxf(tx, 1e-30f);
            #pragma unroll
            for (int r = 0; r < 4; ++r) { az[r] = nz[r] * iz; ax[r] = nx[r] * ix; }
        } else {
            #pragma unroll
            for (int r = 0; r < 4; ++r) { az[r] = nz[r]; ax[r] = nx[r]; }
        }
    }

    // p^2 = tr(Cz64 Cx64)/(tr(Cz64) tr(Cx64)); 3 interleaved reduces
    float tz = dg ? az[lnib & 3] : 0.0f;
    float tx = dg ? ax[lnib & 3] : 0.0f;
    float dt = az[0]*ax[0] + az[1]*ax[1] + az[2]*ax[2] + az[3]*ax[3];
    #pragma unroll
    for (int off = 1; off < 64; off <<= 1) {
        tz += __shfl_xor(tz, off, 64);
        tx += __shfl_xor(tx, off, 64);
        dt += __shfl_xor(dt, off, 64);
    }
    if (lane == 0) psum[wave] = dt / fmaxf(tz * tx, 1e-30f);
    __syncthreads();
    if (threadIdx.x == 0)
        part[blockIdx.x] = psum[0] + psum[1] + psum[2] + psum[3];   // plain store, no atomic
}

// ---------------------------------------------------------------- final: reduce partials + combine
__global__ __launch_bounds__(256) void final_kernel(const float* __restrict__ accum,
                                                    const float* __restrict__ part,
                                                    float* __restrict__ out) {
    __shared__ float ws[4];
    int tid = threadIdx.x;
    float s = 0.0f;
    for (int i = tid; i < NPART; i += 256) s += part[i];
    #pragma unroll
    for (int off = 32; off >= 1; off >>= 1) s += __shfl_down(s, off, 64);
    if ((tid & 63) == 0) ws[tid >> 6] = s;
    __syncthreads();
    if (tid == 0) {
        float dot2  = ws[0] + ws[1] + ws[2] + ws[3];
        float recon = accum[0] * (1.0f / (float)(B_N * D_DIM));
        float tsa   = 2.0f - 2.0f * (dot2 * (1.0f / (float)B_N));
        out[0] = recon + 0.1f * tsa;
    }
}

extern "C" void kernel_launch(void* const* d_in, const int* in_sizes, int n_in,
                              void* d_out, int out_size, void* d_ws, size_t ws_size,
                              hipStream_t stream) {
    const float* outputs = (const float*)d_in[0];
    const float* targets = (const float*)d_in[1];
    const float* latent  = (const float*)d_in[2];
    const float* raw     = (const float*)d_in[3];

    float* accum         = (float*)d_ws;
    float* sq            = (float*)((char*)d_ws + WS_SQ_OFF);
    float* T             = (float*)((char*)d_ws + WS_T_OFF);
    unsigned short* rawh = (unsigned short*)((char*)d_ws + WS_RAWH_OFF);
    unsigned short* rawl = (unsigned short*)((char*)d_ws + WS_RAWL_OFF);
    unsigned short* lath = (unsigned short*)((char*)d_ws + WS_LATH_OFF);
    unsigned short* latl = (unsigned short*)((char*)d_ws + WS_LATL_OFF);
    unsigned* nbrG       = (unsigned*)((char*)d_ws + WS_NBR_OFF);
    float* part          = (float*)((char*)d_ws + WS_PART_OFF);

    const float4* rawv = (const float4*)raw;
    const float4* latv = (const float4*)latent;

    hipMemsetAsync(d_ws, 0, 256, stream);  // zero accum
    prep_kernel<<<B_N / 256, 256, 0, stream>>>(rawv, latv, (const float4*)outputs,
                                               (const float4*)targets, sq, rawh, rawl,
                                               lath, latl, accum);
    thresh_kernel<<<B_N / 16, 256, 0, stream>>>(rawv, rawh, sq, T);
    scan_kernel<<<B_N / 32, 512, 0, stream>>>(rawh, rawl, sq, T, nbrG);
    eig_kernel<<<B_N / 4, 256, 0, stream>>>(lath, latl, rawh, rawl, nbrG, part);
    final_kernel<<<1, 256, 0, stream>>>(accum, part, (float*)d_out);
}